// Round 6
// baseline (98.350 us; speedup 1.0000x reference)
//
#include <hip/hip_runtime.h>
#include <hip/hip_bf16.h>
#include <math.h>

#define NEG 0.1f
#define EPSV 1e-8f

constexpr int D  = 1024;
constexpr int BK = 32;        // k per step (4 slots of 8 bf16)
constexpr int NK = D / BK;    // 32
constexpr int BN = 128;
constexpr int BM = 128;       // 2 batch-groups x 64 padded rows

typedef __bf16 bf16x8 __attribute__((ext_vector_type(8)));
typedef float  f32x4  __attribute__((ext_vector_type(4)));

__device__ __forceinline__ bf16x8 cvt8(float4 a, float4 b) {
    bf16x8 r;
    r[0] = (__bf16)a.x; r[1] = (__bf16)a.y; r[2] = (__bf16)a.z; r[3] = (__bf16)a.w;
    r[4] = (__bf16)b.x; r[5] = (__bf16)b.y; r[6] = (__bf16)b.z; r[7] = (__bf16)b.w;
    return r;
}

// async global->LDS, 16B per lane; LDS dest is wave-uniform base + lane*16
__device__ __forceinline__ void gld_lds16(const __bf16* g, __bf16* l) {
    __builtin_amdgcn_global_load_lds(
        (__attribute__((address_space(1))) void*)(size_t)(const void*)g,
        (__attribute__((address_space(3))) void*)l,
        16, 0, 0);
}

// W f32 [1024][1024] -> bf16 pre-swizzled, key = e&3 within each 32-elem chunk:
// dst slot s holds orig slot s^(e&3)
__global__ __launch_bounds__(256)
void convert_w(const float* __restrict__ W0, const float* __restrict__ W1,
               __bf16* __restrict__ O0, __bf16* __restrict__ O1)
{
    int g = blockIdx.x * 256 + threadIdx.x;       // 2*1024*128 slot tasks
    const float* src = (g < 131072) ? W0 : W1;
    __bf16*      dst = (g < 131072) ? O0 : O1;
    g &= 131071;
    const int e  = g >> 7;
    const int sl = g & 127;
    const int ch = sl >> 2, si = sl & 3;
    const int ss = (ch << 2) | (si ^ (e & 3));
    const float* p = src + (size_t)e * D + ss * 8;
    *(bf16x8*)(dst + (size_t)e * D + sl * 8) =
        cvt8(*(const float4*)p, *(const float4*)(p + 4));
}

// ---------------- GEMM body ----------------
// out[b][e] = scale * sum_{t<lb[b]} leaky( dot(A[b][t][:], W[e][:]) + bias[e] )
// A: f32 [128][srcrows][1024] reg-staged (cvt+swizzled ds_write);
// W: bf16 pre-swizzled, global_load_lds. BK=32 dbuf, counted vmcnt,
// XCD batch-partition, mi-granular row skip.
__device__ __forceinline__ void vsum_body(
    const float* __restrict__ A, int srcrows,
    const __bf16* __restrict__ Wsw,
    const float* __restrict__ bias, const int* __restrict__ lens, int rowsv,
    float scale, float* __restrict__ out, int wg, __bf16* sm)
{
    __bf16* Ab0 = sm;            // [128][32]
    __bf16* Ab1 = sm + 4096;
    __bf16* Bb0 = sm + 8192;
    __bf16* Bb1 = sm + 12288;

    const int tid  = threadIdx.x;
    const int wid  = tid >> 6;
    const int lane = tid & 63;
    const int r16  = lane & 15;
    const int kg   = lane >> 4;

    // XCD-aware: each XCD owns 16 batches x all 8 e-columns
    const int xcd = wg & 7;
    const int idx = wg >> 3;                // 0..63
    const int jj  = idx & 7;                // e-column
    const int y   = xcd * 8 + (idx >> 3);   // batch-group 0..63
    const int e0  = jj * BN;
    const int b0  = y * 2;

    int lb0 = rowsv, lb1 = rowsv;
    if (lens) {
        const int l0 = lens[b0], l1 = lens[b0 + 1];
        lb0 = l0 < 64 ? l0 : 64;
        lb1 = l1 < 64 ? l1 : 64;
    }
    bool mact[8];
    #pragma unroll
    for (int mi = 0; mi < 8; ++mi)
        mact[mi] = ((mi & 3) * 16) < ((mi < 4) ? lb0 : lb1);

    // A staging tasks: 512 = 128 rows x 4 origin-slots(8 f32); 2 per thread
    const float* pA[2];
    int aoff[2];
    #pragma unroll
    for (int p = 0; p < 2; ++p) {
        const int task = tid + p * 256;
        const int row = task >> 2, h = task & 3;
        const int g = row >> 6, t = row & 63;
        const int st = t < srcrows ? t : srcrows - 1;   // clamp dead rows (masked later)
        pA[p] = A + ((size_t)(b0 + g) * srcrows + st) * D + h * 8;
        aoff[p] = row * 32 + ((h ^ (row & 3)) << 3);
    }
    // B gload tasks: 2 calls/wave, 16 rows x 64B each, linear LDS dest
    const __bf16* pB[2];
    int boff[2];
    #pragma unroll
    for (int cc = 0; cc < 2; ++cc) {
        const int rbase = (wid * 2 + cc) * 16;
        pB[cc] = Wsw + (size_t)(e0 + rbase + (lane >> 2)) * D + (lane & 3) * 8;
        boff[cc] = rbase * 32;
    }
    const int sws     = (kg ^ (r16 & 3)) << 3;
    const int ra_off  = r16 * 32 + sws;                 // + mi*512
    const int rb_off  = (wid * 32 + r16) * 32 + sws;    // + ni*512

    f32x4 acc[8][2];
    #pragma unroll
    for (int mi = 0; mi < 8; ++mi) {
        acc[mi][0] = (f32x4){0.f, 0.f, 0.f, 0.f};
        acc[mi][1] = (f32x4){0.f, 0.f, 0.f, 0.f};
    }

    float4 raA[2][2], raB[2][2];   // two named reg banks (static indexing)

    auto loadA = [&](int ks, float4 (&rr)[2][2]) {
        #pragma unroll
        for (int p = 0; p < 2; ++p) {
            const float* q = pA[p] + ks * 32;
            rr[p][0] = *(const float4*)q;
            rr[p][1] = *(const float4*)(q + 4);
        }
    };
    auto stageA = [&](float4 (&rr)[2][2], __bf16* buf) {
        #pragma unroll
        for (int p = 0; p < 2; ++p)
            *(bf16x8*)&buf[aoff[p]] = cvt8(rr[p][0], rr[p][1]);
    };
    auto issueB = [&](int ks, __bf16* buf) {
        #pragma unroll
        for (int cc = 0; cc < 2; ++cc)
            gld_lds16(pB[cc] + ks * 32, buf + boff[cc]);
    };
    auto compute = [&](__bf16* Ac, __bf16* Bc) {
        bf16x8 bfr0 = *(bf16x8*)&Bc[rb_off];
        bf16x8 bfr1 = *(bf16x8*)&Bc[rb_off + 512];
        #pragma unroll
        for (int mi = 0; mi < 8; ++mi) {
            if (!mact[mi]) continue;
            bf16x8 af = *(bf16x8*)&Ac[mi * 512 + ra_off];
            acc[mi][0] = __builtin_amdgcn_mfma_f32_16x16x32_bf16(af, bfr0, acc[mi][0], 0, 0, 0);
            acc[mi][1] = __builtin_amdgcn_mfma_f32_16x16x32_bf16(af, bfr1, acc[mi][1], 0, 0, 0);
        }
    };

    auto halfstep = [&](int ks, __bf16* Ac, __bf16* An, __bf16* Bc, __bf16* Bn,
                        float4 (&rl)[2][2], float4 (&rs)[2][2]) {
        if (ks + 1 < NK) issueB(ks + 1, Bn);       // +2 vmem
        if (ks + 2 < NK) loadA(ks + 2, rl);        // +4 vmem
        // wait: B(ks) + A(ks+1) landed; keep B(ks+1)=2 + A(ks+2)=4 in flight
        if (ks + 2 < NK)      asm volatile("s_waitcnt vmcnt(6)" ::: "memory");
        else if (ks + 1 < NK) asm volatile("s_waitcnt vmcnt(2)" ::: "memory");
        else                  asm volatile("s_waitcnt vmcnt(0)" ::: "memory");
        __builtin_amdgcn_s_barrier();              // publish Bsm[cur] (+Asm[cur] via prev lgkm)
        __builtin_amdgcn_sched_barrier(0);
        if (ks + 1 < NK) stageA(rs, An);           // ds_write next A while MFMAing cur
        compute(Ac, Bc);
        __builtin_amdgcn_sched_barrier(0);
        asm volatile("s_waitcnt lgkmcnt(0)" ::: "memory");  // commit ds_writes
        __builtin_amdgcn_s_barrier();              // publish Asm[next]; reads of cur done
    };

    // prologue: B(0) async; A(0),A(1) to regs; stage A(0)
    issueB(0, Bb0);
    loadA(0, raA);
    loadA(1, raB);
    asm volatile("s_waitcnt vmcnt(4)" ::: "memory");   // B(0)+A(0) landed; keep A(1)
    stageA(raA, Ab0);
    asm volatile("s_waitcnt lgkmcnt(0)" ::: "memory");

    for (int ks = 0; ks < NK; ks += 2) {
        halfstep(ks,     Ab0, Ab1, Bb0, Bb1, raA, raB);  // A(even)->raA, stage A(odd)
        halfstep(ks + 1, Ab1, Ab0, Bb1, Bb0, raB, raA);
    }

    // ---- epilogue: bias + leaky + per-row mask + reduce over rows ----
    float bv[2];
    #pragma unroll
    for (int ni = 0; ni < 2; ++ni) bv[ni] = bias[e0 + wid * 32 + ni * 16 + r16];

    float part[2][2];
    part[0][0] = part[0][1] = part[1][0] = part[1][1] = 0.f;

    #pragma unroll
    for (int mi = 0; mi < 8; ++mi) {
        #pragma unroll
        for (int j = 0; j < 4; ++j) {
            const int row = mi * 16 + kg * 4 + j;
            const int g   = row >> 6;
            const int t   = row & 63;
            const int lb  = g ? lb1 : lb0;
            if (t < lb) {
                #pragma unroll
                for (int ni = 0; ni < 2; ++ni) {
                    float v = acc[mi][ni][j] + bv[ni];
                    v = v > 0.f ? v : NEG * v;       // leaky before mask (ref order)
                    if (g) part[1][ni] += v; else part[0][ni] += v;
                }
            }
        }
    }
    #pragma unroll
    for (int g = 0; g < 2; ++g)
        #pragma unroll
        for (int ni = 0; ni < 2; ++ni) {
            part[g][ni] += __shfl_xor(part[g][ni], 16, 64);
            part[g][ni] += __shfl_xor(part[g][ni], 32, 64);
        }
    const float v = (kg == 0) ? part[0][0] : (kg == 1) ? part[0][1]
                  : (kg == 2) ? part[1][0] : part[1][1];
    const int gg = kg >> 1, nn = kg & 1;
    out[(size_t)(b0 + gg) * D + e0 + wid * 32 + nn * 16 + r16] = scale * v;
}

// cap_vec[c] = l2norm( sum_{t<len} cap[c,t,:] / len )  (one block, 256 thr)
__device__ __forceinline__ void capvec_part(
    const float* __restrict__ cap, const int* __restrict__ lens,
    float* __restrict__ capv, int c, float* wsum)
{
    const int tid = threadIdx.x;
    const int len = lens[c];
    const float* base = cap + (size_t)c * 64 * D + tid * 4;
    float4 acc = make_float4(0.f, 0.f, 0.f, 0.f);
    for (int t = 0; t < len; ++t) {
        float4 v = *(const float4*)(base + (size_t)t * D);
        acc.x += v.x; acc.y += v.y; acc.z += v.z; acc.w += v.w;
    }
    const float inv = 1.f / (float)len;
    acc.x *= inv; acc.y *= inv; acc.z *= inv; acc.w *= inv;
    float ss = acc.x * acc.x + acc.y * acc.y + acc.z * acc.z + acc.w * acc.w;
    #pragma unroll
    for (int o = 32; o > 0; o >>= 1) ss += __shfl_xor(ss, o, 64);
    if ((tid & 63) == 0) wsum[tid >> 6] = ss;
    __syncthreads();
    const float total = wsum[0] + wsum[1] + wsum[2] + wsum[3];
    const float r = 1.f / (sqrtf(total) + EPSV);
    float4 o4 = make_float4(acc.x * r, acc.y * r, acc.z * r, acc.w * r);
    *(float4*)(capv + (size_t)c * D + tid * 4) = o4;
}

// one grid: [0,128) capvec | [128,640) cap-GEMM | [640,1152) img-GEMM
__global__ __launch_bounds__(256, 3)
void fused_union(const float* __restrict__ cap, const float* __restrict__ img,
                 const __bf16* __restrict__ wtb, const __bf16* __restrict__ wib,
                 const float* __restrict__ bvt, const float* __restrict__ bvi,
                 const int* __restrict__ lens, float scale,
                 float* __restrict__ ctxbar, float* __restrict__ vbar,
                 float* __restrict__ capv)
{
    extern __shared__ __bf16 sm[];
    int bid = blockIdx.x;
    if (bid < 128) { capvec_part(cap, lens, capv, bid, (float*)sm); return; }
    bid -= 128;
    if (bid < 512) vsum_body(cap, 64, wtb, bvt, lens,   64, scale, ctxbar, bid, sm);
    else           vsum_body(img, 36, wib, bvi, nullptr, 36, scale, vbar, bid - 512, sm);
}

// sims[i,c] = (g*<ctx_c,cap_c> + <vb_i,cap_c>) /
//             (sqrt(g^2*|ctx_c|^2 + 2g*<ctx_c,vb_i> + |vb_i|^2) + eps)
__global__ __launch_bounds__(256)
void sims_kernel(const float* __restrict__ ctxbar, const float* __restrict__ vbar,
                 const float* __restrict__ capv, const float* __restrict__ gptr,
                 float* __restrict__ out)
{
    constexpr int KC3 = 256;
    __shared__ float Cx[16][KC3 + 4];
    __shared__ float Vb[16][KC3 + 4];
    __shared__ float Cp[16][KC3 + 4];
    const int tid = threadIdx.x;
    const int tx = tid & 15;
    const int ty = tid >> 4;
    const int c0 = blockIdx.x * 16, i0 = blockIdx.y * 16;

    float s1 = 0.f, s2 = 0.f, s3 = 0.f, s4 = 0.f, s5 = 0.f;
    for (int k0 = 0; k0 < D; k0 += KC3) {
        for (int idx = tid; idx < 16 * (KC3 / 4); idx += 256) {
            int row = idx >> 6;
            int k4  = (idx & 63) << 2;
            *(float4*)&Cx[row][k4] = *(const float4*)(ctxbar + (size_t)(c0 + row) * D + k0 + k4);
            *(float4*)&Vb[row][k4] = *(const float4*)(vbar   + (size_t)(i0 + row) * D + k0 + k4);
            *(float4*)&Cp[row][k4] = *(const float4*)(capv   + (size_t)(c0 + row) * D + k0 + k4);
        }
        __syncthreads();
        #pragma unroll 8
        for (int k4 = 0; k4 < KC3 / 4; ++k4) {
            float4 xc = *(const float4*)&Cx[tx][k4 * 4];
            float4 xv = *(const float4*)&Vb[ty][k4 * 4];
            float4 xp = *(const float4*)&Cp[tx][k4 * 4];
            s1 += xc.x * xv.x + xc.y * xv.y + xc.z * xv.z + xc.w * xv.w;
            s2 += xv.x * xp.x + xv.y * xp.y + xv.z * xp.z + xv.w * xp.w;
            s3 += xc.x * xp.x + xc.y * xp.y + xc.z * xp.z + xc.w * xp.w;
            s4 += xc.x * xc.x + xc.y * xc.y + xc.z * xc.z + xc.w * xc.w;
            s5 += xv.x * xv.x + xv.y * xv.y + xv.z * xv.z + xv.w * xv.w;
        }
        __syncthreads();
    }
    const float g = *gptr;
    const float num = g * s3 + s2;
    const float den = sqrtf(g * g * s4 + 2.f * g * s1 + s5) + EPSV;
    out[(size_t)(i0 + ty) * 128 + (c0 + tx)] = num / den;
}

extern "C" void kernel_launch(void* const* d_in, const int* in_sizes, int n_in,
                              void* d_out, int out_size, void* d_ws, size_t ws_size,
                              hipStream_t stream)
{
    const float* img  = (const float*)d_in[0];   // [128,36,1024]
    const float* cap  = (const float*)d_in[1];   // [128,64,1024]
    const int*   lens = (const int*)  d_in[2];   // [128]
    const float* Wvi  = (const float*)d_in[7];   // [1024,1024]
    const float* bvi  = (const float*)d_in[8];
    const float* Wvt  = (const float*)d_in[9];   // [1024,1024]
    const float* bvt  = (const float*)d_in[10];
    const float* gamma = (const float*)d_in[11];
    // Wq/bq/Wk/bk/alpha/beta dead: softmax then mean over same axis == 1/R.

    float* out = (float*)d_out;

    // ws: wtb 2M | wib 2M | ctxbar 512K | vbar 512K | capv 512K  (5.5 MB)
    __bf16* wtb = (__bf16*)d_ws;
    __bf16* wib = wtb + (size_t)1024 * 1024;
    float* ctxbar = (float*)(wib + (size_t)1024 * 1024);
    float* vbar   = ctxbar + 128 * 1024;
    float* capv   = vbar   + 128 * 1024;

    const float scale = 1.f / 36.f;      // attn_mean == 1/R exactly; also v_img mean
    dim3 blk(256);
    convert_w<<<dim3(1024), blk, 0, stream>>>(Wvt, Wvi, wtb, wib);
    fused_union<<<dim3(1152), blk, 32768, stream>>>(cap, img, wtb, wib, bvt, bvi,
                                                    lens, scale, ctxbar, vbar, capv);
    sims_kernel<<<dim3(8, 8), blk, 0, stream>>>(ctxbar, vbar, capv, gamma, out);
}

// Round 7
// 83.958 us; speedup vs baseline: 1.1714x; 1.1714x over previous
//
#include <hip/hip_runtime.h>
#include <hip/hip_bf16.h>
#include <math.h>

#define NEG 0.1f
#define EPSV 1e-8f

constexpr int D = 1024;

typedef __bf16 bf16x8 __attribute__((ext_vector_type(8)));
typedef __bf16 bf16x4 __attribute__((ext_vector_type(4)));
typedef float  f32x4  __attribute__((ext_vector_type(4)));

__device__ __forceinline__ bf16x8 cvt8(float4 a, float4 b) {
    bf16x8 r;
    r[0] = (__bf16)a.x; r[1] = (__bf16)a.y; r[2] = (__bf16)a.z; r[3] = (__bf16)a.w;
    r[4] = (__bf16)b.x; r[5] = (__bf16)b.y; r[6] = (__bf16)b.z; r[7] = (__bf16)b.w;
    return r;
}

// async global->LDS, 16B/lane; LDS dest = wave-uniform base + lane*16
__device__ __forceinline__ void gld_lds16(const __bf16* g, __bf16* l) {
    __builtin_amdgcn_global_load_lds(
        (__attribute__((address_space(1))) void*)(size_t)(const void*)g,
        (__attribute__((address_space(3))) void*)l,
        16, 0, 0);
}

// ---------- fused conversion ----------
// blocks [0,4096):   W x2 (1024 blk) + img padded to 64 rows/batch, write rows<48
//                    (rows 36-47 zeros; 48-63 never written/used). key = row&7.
// blocks [4096,4608): cap -> bf16 swizzled + per-(c,quarter) masked partial sums.
__global__ __launch_bounds__(256)
void convert_all(const float* __restrict__ Wvt, const float* __restrict__ Wvi,
                 const float* __restrict__ img, const float* __restrict__ cap,
                 const int* __restrict__ lens,
                 __bf16* __restrict__ wtb, __bf16* __restrict__ wib,
                 __bf16* __restrict__ imgb, __bf16* __restrict__ capb,
                 float* __restrict__ cappart)
{
    const int bid = blockIdx.x;
    if (bid < 4096) {
        int g = bid * 256 + threadIdx.x;
        if (g < 262144) {
            // W path: dst slot s holds orig slot s^(e&7)
            const float* src = (g < 131072) ? Wvt : Wvi;
            __bf16*      dst = (g < 131072) ? wtb : wib;
            g &= 131071;
            const int e  = g >> 7;
            const int sl = g & 127;
            const int c  = sl >> 3, si = sl & 7;
            const int ss = (c << 3) | (si ^ (e & 7));
            const float* p = src + (size_t)e * D + ss * 8;
            *(bf16x8*)(dst + (size_t)e * D + sl * 8) =
                cvt8(*(const float4*)p, *(const float4*)(p + 4));
        } else {
            // img path: [128][36] -> [128][64] rows, write t<48, key t&7
            const int gg = g - 262144;            // < 786432
            const int Rd = gg >> 7, sl = gg & 127;
            const int c  = Rd / 48, t = Rd - c * 48;
            bf16x8 w;
            if (t < 36) {
                const int ch = sl >> 3, u = sl & 7;
                const int s2 = (ch << 3) | (u ^ (t & 7));
                const float* p = img + (size_t)(c * 36 + t) * D + s2 * 8;
                w = cvt8(*(const float4*)p, *(const float4*)(p + 4));
            } else {
                #pragma unroll
                for (int j = 0; j < 8; ++j) w[j] = (__bf16)0.f;
            }
            *(bf16x8*)(imgb + (size_t)(c * 64 + t) * D + sl * 8) = w;
        }
    } else {
        // cap path: (c, quarter) converts 16 rows + masked partial sums
        const int cb2 = bid - 4096;               // 0..511
        const int c = cb2 >> 2, q = cb2 & 3;
        const int tid = threadIdx.x;
        const int col = tid * 4;
        const int cb = col & ~63, u = (col >> 3) & 7, lo = col & 7;
        const int len = lens[c];
        const float* src = cap + (size_t)c * 64 * D + col;
        __bf16* drow = capb + (size_t)c * 64 * D;
        float4 acc = make_float4(0.f, 0.f, 0.f, 0.f);
        #pragma unroll
        for (int tt = 0; tt < 16; ++tt) {
            const int t = q * 16 + tt;
            float4 v = *(const float4*)(src + (size_t)t * D);
            if (t < len) { acc.x += v.x; acc.y += v.y; acc.z += v.z; acc.w += v.w; }
            bf16x4 w;
            w[0] = (__bf16)v.x; w[1] = (__bf16)v.y;
            w[2] = (__bf16)v.z; w[3] = (__bf16)v.w;
            *(bf16x4*)(drow + (size_t)t * D + cb + ((u ^ (t & 7)) << 3) + lo) = w;
        }
        *(float4*)(cappart + ((size_t)q * 128 + c) * D + col) = acc;
    }
}

// cap_vec[c] = l2norm( (sum_q part[q][c]) / len )
__global__ __launch_bounds__(256)
void capfin(const float* __restrict__ cappart, const int* __restrict__ lens,
            float* __restrict__ capv)
{
    const int c = blockIdx.x, tid = threadIdx.x;
    const int col = tid * 4;
    float4 acc = make_float4(0.f, 0.f, 0.f, 0.f);
    #pragma unroll
    for (int q = 0; q < 4; ++q) {
        float4 v = *(const float4*)(cappart + ((size_t)q * 128 + c) * D + col);
        acc.x += v.x; acc.y += v.y; acc.z += v.z; acc.w += v.w;
    }
    const float inv = 1.f / (float)lens[c];
    acc.x *= inv; acc.y *= inv; acc.z *= inv; acc.w *= inv;
    float ss = acc.x * acc.x + acc.y * acc.y + acc.z * acc.z + acc.w * acc.w;
    #pragma unroll
    for (int o = 32; o > 0; o >>= 1) ss += __shfl_xor(ss, o, 64);
    __shared__ float wsum[4];
    if ((tid & 63) == 0) wsum[tid >> 6] = ss;
    __syncthreads();
    const float total = wsum[0] + wsum[1] + wsum[2] + wsum[3];
    const float r = 1.f / (sqrtf(total) + EPSV);
    float4 o4 = make_float4(acc.x * r, acc.y * r, acc.z * r, acc.w * r);
    *(float4*)(capv + (size_t)c * D + col) = o4;
}

// ---------- 8-wave 256x256 GEMM body, BK=64, 2 barriers/tile, counted vmcnt ----
// out[b][e] = scale * sum_{t<lb[b]} leaky( dot(A[b][t][:], W[e][:]) + bias[e] )
// A,W: bf16 pre-swizzled (key row&7 on 16B slots within 128B chunks).
__device__ __forceinline__ void gemm_body(
    const __bf16* __restrict__ Asrc, const __bf16* __restrict__ Wsw,
    const float* __restrict__ bias, const int* __restrict__ lens,
    float scale, float* __restrict__ out, int mb, int nb, __bf16* sm)
{
    __bf16* A0 = sm;              // [256][64]
    __bf16* A1 = sm + 16384;
    __bf16* B0 = sm + 32768;      // [256][64]
    __bf16* B1 = sm + 49152;

    const int tid  = threadIdx.x;
    const int wid  = tid >> 6;     // 0..7
    const int lane = tid & 63;
    const int r16  = lane & 15;
    const int kg   = lane >> 4;
    const int wm   = wid >> 2;     // 0..1 (M half)
    const int wn   = wid & 3;      // 0..3 (N quarter)

    const int r0 = mb * 256;
    const int e0 = nb * 256;
    const int bglobal = mb * 4;

    int lb[2];
    #pragma unroll
    for (int g = 0; g < 2; ++g) {
        const int b = bglobal + wm * 2 + g;
        lb[g] = lens ? (lens[b] < 64 ? lens[b] : 64) : 36;
    }
    bool mact[8];
    #pragma unroll
    for (int mi = 0; mi < 8; ++mi)
        mact[mi] = ((mi & 3) * 16) < lb[mi >> 2];

    // staging: per wave 8 gload_lds per tile (4 A + 4 B), 8 rows x 8 slots per call
    const __bf16* aS = Asrc + (size_t)(r0 + wid * 32 + (lane >> 3)) * D + (lane & 7) * 8;
    const __bf16* bS = Wsw  + (size_t)(e0 + wid * 32 + (lane >> 3)) * D + (lane & 7) * 8;
    const int dstOff = wid * 32 * 64;   // elems

    auto stage = [&](int kt, __bf16* Ad, __bf16* Bd) {
        const int ko = kt * 64;
        #pragma unroll
        for (int c = 0; c < 4; ++c)
            gld_lds16(aS + (size_t)c * 8 * D + ko, Ad + dstOff + c * 512);
        #pragma unroll
        for (int c = 0; c < 4; ++c)
            gld_lds16(bS + (size_t)c * 8 * D + ko, Bd + dstOff + c * 512);
    };

    f32x4 acc[8][4];
    #pragma unroll
    for (int mi = 0; mi < 8; ++mi)
        #pragma unroll
        for (int ni = 0; ni < 4; ++ni)
            acc[mi][ni] = (f32x4){0.f, 0.f, 0.f, 0.f};

    auto compute = [&](__bf16* Ab, __bf16* Bb) {
        #pragma unroll
        for (int ksub = 0; ksub < 2; ++ksub) {
            const int sbase = (ksub << 2) | kg;
            bf16x8 bf[4];
            #pragma unroll
            for (int ni = 0; ni < 4; ++ni) {
                const int row = wn * 64 + ni * 16 + r16;
                bf[ni] = *(const bf16x8*)&Bb[row * 64 + ((sbase ^ (row & 7)) << 3)];
            }
            #pragma unroll
            for (int mh = 0; mh < 2; ++mh) {
                bf16x8 af[4];
                #pragma unroll
                for (int m2 = 0; m2 < 4; ++m2) {
                    if (mact[mh * 4 + m2]) {
                        const int row = wm * 128 + (mh * 4 + m2) * 16 + r16;
                        af[m2] = *(const bf16x8*)&Ab[row * 64 + ((sbase ^ (row & 7)) << 3)];
                    }
                }
                __builtin_amdgcn_s_setprio(1);
                #pragma unroll
                for (int m2 = 0; m2 < 4; ++m2) {
                    if (mact[mh * 4 + m2]) {
                        #pragma unroll
                        for (int ni = 0; ni < 4; ++ni)
                            acc[mh * 4 + m2][ni] = __builtin_amdgcn_mfma_f32_16x16x32_bf16(
                                af[m2], bf[ni], acc[mh * 4 + m2][ni], 0, 0, 0);
                    }
                }
                __builtin_amdgcn_s_setprio(0);
            }
        }
    };

    auto tile = [&](int t, __bf16* Ac, __bf16* Bc, __bf16* An, __bf16* Bn) {
        if (t + 1 < 16) {
            stage(t + 1, An, Bn);                     // next tile's 8 loads in flight
            asm volatile("s_waitcnt vmcnt(8)" ::: "memory");   // current tile landed
        } else {
            asm volatile("s_waitcnt vmcnt(0)" ::: "memory");
        }
        __builtin_amdgcn_s_barrier();                 // all waves' loads visible
        __builtin_amdgcn_sched_barrier(0);
        compute(Ac, Bc);
        __builtin_amdgcn_sched_barrier(0);
        __builtin_amdgcn_s_barrier();                 // reads done before overwrite
    };

    stage(0, A0, B0);
    for (int t = 0; t < 16; t += 2) {
        tile(t,     A0, B0, A1, B1);
        tile(t + 1, A1, B1, A0, B0);
    }

    // ---- epilogue: bias + leaky + row mask + reduce over rows ----
    float bv[4];
    #pragma unroll
    for (int ni = 0; ni < 4; ++ni) bv[ni] = bias[e0 + wn * 64 + ni * 16 + r16];

    float part[2][4];
    #pragma unroll
    for (int g = 0; g < 2; ++g)
        #pragma unroll
        for (int ni = 0; ni < 4; ++ni) part[g][ni] = 0.f;

    #pragma unroll
    for (int mi = 0; mi < 8; ++mi) {
        const int g = mi >> 2;
        #pragma unroll
        for (int j = 0; j < 4; ++j) {
            const int t = (mi & 3) * 16 + kg * 4 + j;
            if (t < lb[g]) {
                #pragma unroll
                for (int ni = 0; ni < 4; ++ni) {
                    float v = acc[mi][ni][j] + bv[ni];
                    v = v > 0.f ? v : NEG * v;        // leaky before mask (ref order)
                    part[g][ni] += v;
                }
            }
        }
    }
    #pragma unroll
    for (int g = 0; g < 2; ++g)
        #pragma unroll
        for (int ni = 0; ni < 4; ++ni) {
            part[g][ni] += __shfl_xor(part[g][ni], 16, 64);
            part[g][ni] += __shfl_xor(part[g][ni], 32, 64);
        }

    // kg -> (g = kg>>1, nh = kg&1); store ni = nh*2, nh*2+1 (static selects)
    float v0, v1;
    if      (kg == 0) { v0 = part[0][0]; v1 = part[0][1]; }
    else if (kg == 1) { v0 = part[0][2]; v1 = part[0][3]; }
    else if (kg == 2) { v0 = part[1][0]; v1 = part[1][1]; }
    else              { v0 = part[1][2]; v1 = part[1][3]; }
    const int g  = kg >> 1, nh = kg & 1;
    const int batch = bglobal + wm * 2 + g;
    float* orow = out + (size_t)batch * D + e0 + wn * 64 + nh * 32 + r16;
    orow[0]  = scale * v0;
    orow[16] = scale * v1;
}

// 256 blocks: xcd = bid&7 owns (op = xcd&1, W-slice nb = xcd>>1); mb = bid>>3.
__global__ __launch_bounds__(512, 2)
void vsum_union(const __bf16* __restrict__ capb, const __bf16* __restrict__ wtb,
                const float* __restrict__ bvt,
                const __bf16* __restrict__ imgb, const __bf16* __restrict__ wib,
                const float* __restrict__ bvi,
                const int* __restrict__ lens, float scale,
                float* __restrict__ ctxbar, float* __restrict__ vbar)
{
    extern __shared__ __bf16 sm[];
    const int bid = blockIdx.x;
    const int xcd = bid & 7;
    const int mb  = bid >> 3;          // 0..31
    const int nb  = xcd >> 1;          // 0..3
    if (!(xcd & 1))
        gemm_body(capb, wtb, bvt, lens,   scale, ctxbar, mb, nb, sm);
    else
        gemm_body(imgb, wib, bvi, nullptr, scale, vbar,  mb, nb, sm);
}

// sims[i,c] = (g*<ctx_c,cap_c> + <vb_i,cap_c>) /
//             (sqrt(g^2*|ctx_c|^2 + 2g*<ctx_c,vb_i> + |vb_i|^2) + eps)
__global__ __launch_bounds__(256)
void sims_kernel(const float* __restrict__ ctxbar, const float* __restrict__ vbar,
                 const float* __restrict__ capv, const float* __restrict__ gptr,
                 float* __restrict__ out)
{
    constexpr int KC3 = 256;
    __shared__ float Cx[16][KC3 + 4];
    __shared__ float Vb[16][KC3 + 4];
    __shared__ float Cp[16][KC3 + 4];
    const int tid = threadIdx.x;
    const int tx = tid & 15;
    const int ty = tid >> 4;
    const int c0 = blockIdx.x * 16, i0 = blockIdx.y * 16;

    float s1 = 0.f, s2 = 0.f, s3 = 0.f, s4 = 0.f, s5 = 0.f;
    for (int k0 = 0; k0 < D; k0 += KC3) {
        for (int idx = tid; idx < 16 * (KC3 / 4); idx += 256) {
            int row = idx >> 6;
            int k4  = (idx & 63) << 2;
            *(float4*)&Cx[row][k4] = *(const float4*)(ctxbar + (size_t)(c0 + row) * D + k0 + k4);
            *(float4*)&Vb[row][k4] = *(const float4*)(vbar   + (size_t)(i0 + row) * D + k0 + k4);
            *(float4*)&Cp[row][k4] = *(const float4*)(capv   + (size_t)(c0 + row) * D + k0 + k4);
        }
        __syncthreads();
        #pragma unroll 8
        for (int k4 = 0; k4 < KC3 / 4; ++k4) {
            float4 xc = *(const float4*)&Cx[tx][k4 * 4];
            float4 xv = *(const float4*)&Vb[ty][k4 * 4];
            float4 xp = *(const float4*)&Cp[tx][k4 * 4];
            s1 += xc.x * xv.x + xc.y * xv.y + xc.z * xv.z + xc.w * xv.w;
            s2 += xv.x * xp.x + xv.y * xp.y + xv.z * xp.z + xv.w * xp.w;
            s3 += xc.x * xp.x + xc.y * xp.y + xc.z * xp.z + xc.w * xp.w;
            s4 += xc.x * xc.x + xc.y * xc.y + xc.z * xc.z + xc.w * xc.w;
            s5 += xv.x * xv.x + xv.y * xv.y + xv.z * xv.z + xv.w * xv.w;
        }
        __syncthreads();
    }
    const float g = *gptr;
    const float num = g * s3 + s2;
    const float den = sqrtf(g * g * s4 + 2.f * g * s1 + s5) + EPSV;
    out[(size_t)(i0 + ty) * 128 + (c0 + tx)] = num / den;
}

extern "C" void kernel_launch(void* const* d_in, const int* in_sizes, int n_in,
                              void* d_out, int out_size, void* d_ws, size_t ws_size,
                              hipStream_t stream)
{
    const float* img  = (const float*)d_in[0];   // [128,36,1024]
    const float* cap  = (const float*)d_in[1];   // [128,64,1024]
    const int*   lens = (const int*)  d_in[2];   // [128]
    const float* Wvi  = (const float*)d_in[7];   // [1024,1024]
    const float* bvi  = (const float*)d_in[8];
    const float* Wvt  = (const float*)d_in[9];   // [1024,1024]
    const float* bvt  = (const float*)d_in[10];
    const float* gamma = (const float*)d_in[11];
    // Wq/bq/Wk/bk/alpha/beta dead: softmax then mean over same axis == 1/R.

    float* out = (float*)d_out;

    // ws: wtb 2M | wib 2M | capb 16M | imgb 16M | ctx .5 | vb .5 | capv .5 | cappart 2M
    __bf16* wtb  = (__bf16*)d_ws;
    __bf16* wib  = wtb + (size_t)1024 * 1024;
    __bf16* capb = wib + (size_t)1024 * 1024;            // 128*64*1024
    __bf16* imgb = capb + (size_t)128 * 64 * 1024;       // 128*64*1024 (rows 48-63 unused)
    float* ctxbar  = (float*)(imgb + (size_t)128 * 64 * 1024);
    float* vbar    = ctxbar + 128 * 1024;
    float* capv    = vbar   + 128 * 1024;
    float* cappart = capv   + 128 * 1024;                // 4*128*1024

    const float scale = 1.f / 36.f;      // attn_mean == 1/R exactly; also v_img mean
    dim3 blk(256);

    hipFuncSetAttribute((const void*)vsum_union,
                        hipFuncAttributeMaxDynamicSharedMemorySize, 131072);

    convert_all<<<dim3(4608), blk, 0, stream>>>(Wvt, Wvi, img, cap, lens,
                                                wtb, wib, imgb, capb, cappart);
    capfin<<<dim3(128), blk, 0, stream>>>(cappart, lens, capv);
    vsum_union<<<dim3(256), dim3(512), 131072, stream>>>(capb, wtb, bvt,
                                                         imgb, wib, bvi,
                                                         lens, scale, ctxbar, vbar);
    sims_kernel<<<dim3(8, 8), blk, 0, stream>>>(ctxbar, vbar, capv, gamma, out);
}

// Round 8
// 80.843 us; speedup vs baseline: 1.2165x; 1.0385x over previous
//
#include <hip/hip_runtime.h>
#include <hip/hip_bf16.h>
#include <math.h>

#define NEG 0.1f
#define EPSV 1e-8f

constexpr int D = 1024;
constexpr int KTILES = 16;    // K-tiles of 64

typedef __bf16 bf16x8 __attribute__((ext_vector_type(8)));
typedef __bf16 bf16x4 __attribute__((ext_vector_type(4)));
typedef float  f32x4  __attribute__((ext_vector_type(4)));

__device__ __forceinline__ bf16x8 cvt8(float4 a, float4 b) {
    bf16x8 r;
    r[0] = (__bf16)a.x; r[1] = (__bf16)a.y; r[2] = (__bf16)a.z; r[3] = (__bf16)a.w;
    r[4] = (__bf16)b.x; r[5] = (__bf16)b.y; r[6] = (__bf16)b.z; r[7] = (__bf16)b.w;
    return r;
}

// async global->LDS, 16B/lane; LDS dest = wave-uniform base + lane*16
__device__ __forceinline__ void gld_lds16(const __bf16* g, __bf16* l) {
    __builtin_amdgcn_global_load_lds(
        (__attribute__((address_space(1))) void*)(size_t)(const void*)g,
        (__attribute__((address_space(3))) void*)l,
        16, 0, 0);
}

// ---------- fused conversion (unchanged from R7) ----------
__global__ __launch_bounds__(256)
void convert_all(const float* __restrict__ Wvt, const float* __restrict__ Wvi,
                 const float* __restrict__ img, const float* __restrict__ cap,
                 const int* __restrict__ lens,
                 __bf16* __restrict__ wtb, __bf16* __restrict__ wib,
                 __bf16* __restrict__ imgb, __bf16* __restrict__ capb,
                 float* __restrict__ cappart)
{
    const int bid = blockIdx.x;
    if (bid < 4096) {
        int g = bid * 256 + threadIdx.x;
        if (g < 262144) {
            // W path: dst slot s holds orig slot s^(e&7)
            const float* src = (g < 131072) ? Wvt : Wvi;
            __bf16*      dst = (g < 131072) ? wtb : wib;
            g &= 131071;
            const int e  = g >> 7;
            const int sl = g & 127;
            const int c  = sl >> 3, si = sl & 7;
            const int ss = (c << 3) | (si ^ (e & 7));
            const float* p = src + (size_t)e * D + ss * 8;
            *(bf16x8*)(dst + (size_t)e * D + sl * 8) =
                cvt8(*(const float4*)p, *(const float4*)(p + 4));
        } else {
            // img path: [128][36] -> [128][64] rows, write t<48, key t&7
            const int gg = g - 262144;            // < 786432
            const int Rd = gg >> 7, sl = gg & 127;
            const int c  = Rd / 48, t = Rd - c * 48;
            bf16x8 w;
            if (t < 36) {
                const int ch = sl >> 3, u = sl & 7;
                const int s2 = (ch << 3) | (u ^ (t & 7));
                const float* p = img + (size_t)(c * 36 + t) * D + s2 * 8;
                w = cvt8(*(const float4*)p, *(const float4*)(p + 4));
            } else {
                #pragma unroll
                for (int j = 0; j < 8; ++j) w[j] = (__bf16)0.f;
            }
            *(bf16x8*)(imgb + (size_t)(c * 64 + t) * D + sl * 8) = w;
        }
    } else {
        // cap path: (c, quarter) converts 16 rows + masked partial sums
        const int cb2 = bid - 4096;               // 0..511
        const int c = cb2 >> 2, q = cb2 & 3;
        const int tid = threadIdx.x;
        const int col = tid * 4;
        const int cb = col & ~63, u = (col >> 3) & 7, lo = col & 7;
        const int len = lens[c];
        const float* src = cap + (size_t)c * 64 * D + col;
        __bf16* drow = capb + (size_t)c * 64 * D;
        float4 acc = make_float4(0.f, 0.f, 0.f, 0.f);
        #pragma unroll
        for (int tt = 0; tt < 16; ++tt) {
            const int t = q * 16 + tt;
            float4 v = *(const float4*)(src + (size_t)t * D);
            if (t < len) { acc.x += v.x; acc.y += v.y; acc.z += v.z; acc.w += v.w; }
            bf16x4 w;
            w[0] = (__bf16)v.x; w[1] = (__bf16)v.y;
            w[2] = (__bf16)v.z; w[3] = (__bf16)v.w;
            *(bf16x4*)(drow + (size_t)t * D + cb + ((u ^ (t & 7)) << 3) + lo) = w;
        }
        *(float4*)(cappart + ((size_t)q * 128 + c) * D + col) = acc;
    }
}

// cap_vec[c] = l2norm( (sum_q part[q][c]) / len )
__global__ __launch_bounds__(256)
void capfin(const float* __restrict__ cappart, const int* __restrict__ lens,
            float* __restrict__ capv)
{
    const int c = blockIdx.x, tid = threadIdx.x;
    const int col = tid * 4;
    float4 acc = make_float4(0.f, 0.f, 0.f, 0.f);
    #pragma unroll
    for (int q = 0; q < 4; ++q) {
        float4 v = *(const float4*)(cappart + ((size_t)q * 128 + c) * D + col);
        acc.x += v.x; acc.y += v.y; acc.z += v.z; acc.w += v.w;
    }
    const float inv = 1.f / (float)lens[c];
    acc.x *= inv; acc.y *= inv; acc.z *= inv; acc.w *= inv;
    float ss = acc.x * acc.x + acc.y * acc.y + acc.z * acc.z + acc.w * acc.w;
    #pragma unroll
    for (int o = 32; o > 0; o >>= 1) ss += __shfl_xor(ss, o, 64);
    __shared__ float wsum[4];
    if ((tid & 63) == 0) wsum[tid >> 6] = ss;
    __syncthreads();
    const float total = wsum[0] + wsum[1] + wsum[2] + wsum[3];
    const float r = 1.f / (sqrtf(total) + EPSV);
    float4 o4 = make_float4(acc.x * r, acc.y * r, acc.z * r, acc.w * r);
    *(float4*)(capv + (size_t)c * D + col) = o4;
}

// ---------- 8-wave 256x256 GEMM, 8-phase schedule (T3+T4+T5) ----------
// out[b][e] = scale * sum_{t<lb[b]} leaky( dot(A[b][t][:], W[e][:]) + bias[e] )
// A,W bf16 pre-swizzled (key row&7 on 16B slots). 4 phases per K-tile:
// phase = { ds_read quadrant ops | issue next-tile stages (front-loaded p0/p1)
//           | (p3: vmcnt(0)) | barrier | lgkmcnt(0) | 16 MFMA | barrier }.
template<bool IMG>
__device__ __forceinline__ void gemm_body(
    const __bf16* __restrict__ Asrc, const __bf16* __restrict__ Wsw,
    const float* __restrict__ bias, const int* __restrict__ lens,
    float scale, float* __restrict__ out, int mb, int nb, __bf16* sm)
{
    __bf16* A0 = sm;              // [256][64]
    __bf16* A1 = sm + 16384;
    __bf16* B0 = sm + 32768;      // [256][64]
    __bf16* B1 = sm + 49152;

    const int tid  = threadIdx.x;
    const int wid  = tid >> 6;     // 0..7
    const int lane = tid & 63;
    const int r16  = lane & 15;
    const int kg   = lane >> 4;
    const int wm   = wid >> 2;     // 0..1 (M half)
    const int wn   = wid & 3;      // 0..3 (N quarter)

    const int r0 = mb * 256;
    const int e0 = nb * 256;
    const int bglobal = mb * 4;

    int lb[2];
    #pragma unroll
    for (int g = 0; g < 2; ++g) {
        const int b = bglobal + wm * 2 + g;
        lb[g] = IMG ? 36 : (lens[b] < 64 ? lens[b] : 64);
    }
    bool mact[8];
    #pragma unroll
    for (int mi = 0; mi < 8; ++mi)
        mact[mi] = ((mi & 3) * 16) < lb[mi >> 2];

    // staging: wave stages A rows [wid*32,+32) and B rows [wid*32,+32), 8 rows/call
    const __bf16* aS = Asrc + (size_t)(r0 + wid * 32 + (lane >> 3)) * D + (lane & 7) * 8;
    const __bf16* bS = Wsw  + (size_t)(e0 + wid * 32 + (lane >> 3)) * D + (lane & 7) * 8;
    const int dstOff = wid * 2048;     // wid*32 rows * 64

    auto stageA = [&](int kt, __bf16* Ad) {
        const int ko = kt * 64;
        #pragma unroll
        for (int c = 0; c < 4; ++c) {
            // img: odd-wid waves' rows 48-63 (calls 2,3) are dead-padding; skip
            if (IMG && (wid & 1) && c >= 2) continue;
            gld_lds16(aS + (size_t)c * 8 * D + ko, Ad + dstOff + c * 512);
        }
    };
    auto stageBh = [&](int kt, __bf16* Bd, int h) {
        const int ko = kt * 64;
        #pragma unroll
        for (int c = 0; c < 2; ++c) {
            const int cc = h * 2 + c;
            gld_lds16(bS + (size_t)cc * 8 * D + ko, Bd + dstOff + cc * 512);
        }
    };

    f32x4 acc[8][4];
    #pragma unroll
    for (int mi = 0; mi < 8; ++mi)
        #pragma unroll
        for (int ni = 0; ni < 4; ++ni)
            acc[mi][ni] = (f32x4){0.f, 0.f, 0.f, 0.f};

    // LDS read offsets: row&7 == r16&7 (all row components are multiples of 8)
    const int swk = r16 & 7;
    const int sk0 = ((0 + kg) ^ swk) << 3;       // ksub 0 slot byte/2 offset
    const int sk1 = ((4 + kg) ^ swk) << 3;       // ksub 1
    const int aBase = (wm * 128 + r16) * 64;
    const int bBase = (wn * 64 + r16) * 64;

    auto tile = [&](int t, __bf16* Ac, __bf16* Bc, __bf16* An, __bf16* Bn) {
        const bool more = (t + 1) < KTILES;
        bf16x8 bf[4][2];
        #pragma unroll
        for (int p = 0; p < 4; ++p) {
            // --- ds_read this phase's operands (current tile buffer) ---
            if (p == 0) {
                #pragma unroll
                for (int ni = 0; ni < 4; ++ni) {
                    bf[ni][0] = *(const bf16x8*)&Bc[bBase + ni * 1024 + sk0];
                    bf[ni][1] = *(const bf16x8*)&Bc[bBase + ni * 1024 + sk1];
                }
            }
            bf16x8 af[2][2];
            const bool act0 = mact[2 * p];
            const bool act1 = mact[2 * p + 1];
            if (act0) {
                af[0][0] = *(const bf16x8*)&Ac[aBase + (2 * p) * 1024 + sk0];
                af[0][1] = *(const bf16x8*)&Ac[aBase + (2 * p) * 1024 + sk1];
            }
            if (act1) {
                af[1][0] = *(const bf16x8*)&Ac[aBase + (2 * p + 1) * 1024 + sk0];
                af[1][1] = *(const bf16x8*)&Ac[aBase + (2 * p + 1) * 1024 + sk1];
            }
            // --- issue next tile's staging, front-loaded (p0: A+Bh0, p1: Bh1) ---
            if (more) {
                if (p == 0) { stageA(t + 1, An); stageBh(t + 1, Bn, 0); }
                else if (p == 1) { stageBh(t + 1, Bn, 1); }
            }
            // --- once per tile: drain next tile's loads (issued 2-3 phases ago) ---
            if (p == 3) asm volatile("s_waitcnt vmcnt(0)" ::: "memory");
            __builtin_amdgcn_s_barrier();
            asm volatile("s_waitcnt lgkmcnt(0)" ::: "memory");
            __builtin_amdgcn_sched_barrier(0);
            __builtin_amdgcn_s_setprio(1);
            if (act0) {
                #pragma unroll
                for (int ni = 0; ni < 4; ++ni) {
                    acc[2*p][ni] = __builtin_amdgcn_mfma_f32_16x16x32_bf16(
                        af[0][0], bf[ni][0], acc[2*p][ni], 0, 0, 0);
                    acc[2*p][ni] = __builtin_amdgcn_mfma_f32_16x16x32_bf16(
                        af[0][1], bf[ni][1], acc[2*p][ni], 0, 0, 0);
                }
            }
            if (act1) {
                #pragma unroll
                for (int ni = 0; ni < 4; ++ni) {
                    acc[2*p+1][ni] = __builtin_amdgcn_mfma_f32_16x16x32_bf16(
                        af[1][0], bf[ni][0], acc[2*p+1][ni], 0, 0, 0);
                    acc[2*p+1][ni] = __builtin_amdgcn_mfma_f32_16x16x32_bf16(
                        af[1][1], bf[ni][1], acc[2*p+1][ni], 0, 0, 0);
                }
            }
            __builtin_amdgcn_s_setprio(0);
            __builtin_amdgcn_sched_barrier(0);
            __builtin_amdgcn_s_barrier();
        }
    };

    // prologue: stage tile 0 fully, drain, publish
    stageA(0, A0); stageBh(0, B0, 0); stageBh(0, B0, 1);
    asm volatile("s_waitcnt vmcnt(0)" ::: "memory");
    __builtin_amdgcn_s_barrier();

    for (int t = 0; t < KTILES; t += 2) {
        tile(t,     A0, B0, A1, B1);
        tile(t + 1, A1, B1, A0, B0);
    }

    // ---- epilogue: bias + leaky + row mask + reduce over rows ----
    float bv[4];
    #pragma unroll
    for (int ni = 0; ni < 4; ++ni) bv[ni] = bias[e0 + wn * 64 + ni * 16 + r16];

    float part[2][4];
    #pragma unroll
    for (int g = 0; g < 2; ++g)
        #pragma unroll
        for (int ni = 0; ni < 4; ++ni) part[g][ni] = 0.f;

    #pragma unroll
    for (int mi = 0; mi < 8; ++mi) {
        const int g = mi >> 2;
        #pragma unroll
        for (int j = 0; j < 4; ++j) {
            const int t = (mi & 3) * 16 + kg * 4 + j;
            if (t < lb[g]) {
                #pragma unroll
                for (int ni = 0; ni < 4; ++ni) {
                    float v = acc[mi][ni][j] + bv[ni];
                    v = v > 0.f ? v : NEG * v;        // leaky before mask (ref order)
                    part[g][ni] += v;
                }
            }
        }
    }
    #pragma unroll
    for (int g = 0; g < 2; ++g)
        #pragma unroll
        for (int ni = 0; ni < 4; ++ni) {
            part[g][ni] += __shfl_xor(part[g][ni], 16, 64);
            part[g][ni] += __shfl_xor(part[g][ni], 32, 64);
        }

    float v0, v1;
    if      (kg == 0) { v0 = part[0][0]; v1 = part[0][1]; }
    else if (kg == 1) { v0 = part[0][2]; v1 = part[0][3]; }
    else if (kg == 2) { v0 = part[1][0]; v1 = part[1][1]; }
    else              { v0 = part[1][2]; v1 = part[1][3]; }
    const int g  = kg >> 1, nh = kg & 1;
    const int batch = bglobal + wm * 2 + g;
    float* orow = out + (size_t)batch * D + e0 + wn * 64 + nh * 32 + r16;
    orow[0]  = scale * v0;
    orow[16] = scale * v1;
}

// 256 blocks: xcd = bid&7 owns (op = xcd&1, W-slice nb = xcd>>1); mb = bid>>3.
__global__ __launch_bounds__(512, 2)
void vsum_union(const __bf16* __restrict__ capb, const __bf16* __restrict__ wtb,
                const float* __restrict__ bvt,
                const __bf16* __restrict__ imgb, const __bf16* __restrict__ wib,
                const float* __restrict__ bvi,
                const int* __restrict__ lens, float scale,
                float* __restrict__ ctxbar, float* __restrict__ vbar)
{
    extern __shared__ __bf16 sm[];
    const int bid = blockIdx.x;
    const int xcd = bid & 7;
    const int mb  = bid >> 3;          // 0..31
    const int nb  = xcd >> 1;          // 0..3
    if (!(xcd & 1))
        gemm_body<false>(capb, wtb, bvt, lens,  scale, ctxbar, mb, nb, sm);
    else
        gemm_body<true >(imgb, wib, bvi, nullptr, scale, vbar,  mb, nb, sm);
}

// sims[i,c] = (g*<ctx_c,cap_c> + <vb_i,cap_c>) /
//             (sqrt(g^2*|ctx_c|^2 + 2g*<ctx_c,vb_i> + |vb_i|^2) + eps)
__global__ __launch_bounds__(256)
void sims_kernel(const float* __restrict__ ctxbar, const float* __restrict__ vbar,
                 const float* __restrict__ capv, const float* __restrict__ gptr,
                 float* __restrict__ out)
{
    constexpr int KC3 = 256;
    __shared__ float Cx[16][KC3 + 4];
    __shared__ float Vb[16][KC3 + 4];
    __shared__ float Cp[16][KC3 + 4];
    const int tid = threadIdx.x;
    const int tx = tid & 15;
    const int ty = tid >> 4;
    const int c0 = blockIdx.x * 16, i0 = blockIdx.y * 16;

    float s1 = 0.f, s2 = 0.f, s3 = 0.f, s4 = 0.f, s5 = 0.f;
    for (int k0 = 0; k0 < D; k0 += KC3) {
        for (int idx = tid; idx < 16 * (KC3 / 4); idx += 256) {
            int row = idx >> 6;
            int k4  = (idx & 63) << 2;
            *(float4*)&Cx[row][k4] = *(const float4*)(ctxbar + (size_t)(c0 + row) * D + k0 + k4);
            *(float4*)&Vb[row][k4] = *(const float4*)(vbar   + (size_t)(i0 + row) * D + k0 + k4);
            *(float4*)&Cp[row][k4] = *(const float4*)(capv   + (size_t)(c0 + row) * D + k0 + k4);
        }
        __syncthreads();
        #pragma unroll 8
        for (int k4 = 0; k4 < KC3 / 4; ++k4) {
            float4 xc = *(const float4*)&Cx[tx][k4 * 4];
            float4 xv = *(const float4*)&Vb[ty][k4 * 4];
            float4 xp = *(const float4*)&Cp[tx][k4 * 4];
            s1 += xc.x * xv.x + xc.y * xv.y + xc.z * xv.z + xc.w * xv.w;
            s2 += xv.x * xp.x + xv.y * xp.y + xv.z * xp.z + xv.w * xp.w;
            s3 += xc.x * xp.x + xc.y * xp.y + xc.z * xp.z + xc.w * xp.w;
            s4 += xc.x * xc.x + xc.y * xc.y + xc.z * xc.z + xc.w * xc.w;
            s5 += xv.x * xv.x + xv.y * xv.y + xv.z * xv.z + xv.w * xv.w;
        }
        __syncthreads();
    }
    const float g = *gptr;
    const float num = g * s3 + s2;
    const float den = sqrtf(g * g * s4 + 2.f * g * s1 + s5) + EPSV;
    out[(size_t)(i0 + ty) * 128 + (c0 + tx)] = num / den;
}

extern "C" void kernel_launch(void* const* d_in, const int* in_sizes, int n_in,
                              void* d_out, int out_size, void* d_ws, size_t ws_size,
                              hipStream_t stream)
{
    const float* img  = (const float*)d_in[0];   // [128,36,1024]
    const float* cap  = (const float*)d_in[1];   // [128,64,1024]
    const int*   lens = (const int*)  d_in[2];   // [128]
    const float* Wvi  = (const float*)d_in[7];   // [1024,1024]
    const float* bvi  = (const float*)d_in[8];
    const float* Wvt  = (const float*)d_in[9];   // [1024,1024]
    const float* bvt  = (const float*)d_in[10];
    const float* gamma = (const float*)d_in[11];
    // Wq/bq/Wk/bk/alpha/beta dead: softmax then mean over same axis == 1/R.

    float* out = (float*)d_out;

    // ws: wtb 2M | wib 2M | capb 16M | imgb 16M | ctx .5 | vb .5 | capv .5 | cappart 2M
    __bf16* wtb  = (__bf16*)d_ws;
    __bf16* wib  = wtb + (size_t)1024 * 1024;
    __bf16* capb = wib + (size_t)1024 * 1024;            // 128*64*1024
    __bf16* imgb = capb + (size_t)128 * 64 * 1024;       // 128*64*1024 (rows 48-63 unused)
    float* ctxbar  = (float*)(imgb + (size_t)128 * 64 * 1024);
    float* vbar    = ctxbar + 128 * 1024;
    float* capv    = vbar   + 128 * 1024;
    float* cappart = capv   + 128 * 1024;                // 4*128*1024

    const float scale = 1.f / 36.f;      // attn_mean == 1/R exactly; also v_img mean
    dim3 blk(256);

    hipFuncSetAttribute((const void*)vsum_union,
                        hipFuncAttributeMaxDynamicSharedMemorySize, 131072);

    convert_all<<<dim3(4608), blk, 0, stream>>>(Wvt, Wvi, img, cap, lens,
                                                wtb, wib, imgb, capb, cappart);
    capfin<<<dim3(128), blk, 0, stream>>>(cappart, lens, capv);
    vsum_union<<<dim3(256), dim3(512), 131072, stream>>>(capb, wtb, bvt,
                                                         imgb, wib, bvi,
                                                         lens, scale, ctxbar, vbar);
    sims_kernel<<<dim3(8, 8), blk, 0, stream>>>(ctxbar, vbar, capv, gamma, out);
}